// Round 5
// baseline (839.574 us; speedup 1.0000x reference)
//
#include <hip/hip_runtime.h>

#define DEVI static __device__ __forceinline__
typedef unsigned short u16;
typedef short bf16x8 __attribute__((ext_vector_type(8)));
typedef float f32x4 __attribute__((ext_vector_type(4)));

// ---------------- problem constants ----------------
constexpr int LTOK  = 21952;          // 28^3
constexpr int CDIM  = 192;
constexpr int NHEAD = 6;
constexpr int NTOK  = 343;            // 7^3 tokens per window
constexpr int MROW  = 43904;          // 2 * 21952 = 128 * 343
constexpr int TKV   = 176;            // K/V LDS tile rows (attention)

// ---------------- workspace layout (bytes) ----------------
// attn-out [M,192] f32 (dead after proj) is reused as mbuf (fc2 out).
// qkv [M,576] f32 (dead after attn) region is reused as h [M,768] f32.
constexpr size_t OFF_ATTN = 0;                     // 33,718,272
constexpr size_t OFF_QKV  = 33718272;              // qkv 101,154,816 / h 134,873,088
constexpr size_t OFF_XA   = 168591360;             // proj out f32, token order
constexpr size_t OFF_X1   = 202309632;             // x1 f32
constexpr size_t OFF_RPBT = 236027904;             // rpbT [6][343][343] f32
constexpr size_t OFF_HB   = 238851584;             // hb [2197][6] f32
constexpr size_t OFF_QKVB = 238904832;             // qkv bias [576] f32
constexpr size_t OFF_RMAP = 238908928;             // rowmap [43904] int
constexpr size_t OFF_WSP  = 239084544;             // split+padded weights (u16)
// total need ~= 241,148,928 bytes

// split-weight sub-offsets (u16 element units within WSP)
constexpr int WQKV_HI = 0,      WQKV_LO = 122880;   // Np=640 K=192
constexpr int WPRJ_HI = 245760, WPRJ_LO = 294912;   // Np=256 K=192
constexpr int WFC1_HI = 344064, WFC1_LO = 491520;   // Np=768 K=192
constexpr int WFC2_HI = 638976, WFC2_LO = 835584;   // Np=256 K=768

// ---------------- small helpers ----------------
DEVI float dot4(const float4 a, const float4 b) {
    return a.x*b.x + a.y*b.y + a.z*b.z + a.w*b.w;
}
DEVI float gelu_exact(float x) {
    return 0.5f * x * (1.f + erff(x * 0.70710678118654752440f));
}
DEVI u16 f2bf(float f) {                    // round-to-nearest-even f32 -> bf16
    unsigned u = __float_as_uint(f);
    u += 0x7fffu + ((u >> 16) & 1u);
    return (u16)(u >> 16);
}
DEVI float bf2f(u16 h) { return __uint_as_float(((unsigned)h) << 16); }
DEVI unsigned pk_hi(float a, float b) {     // packed bf16 hi parts
    return (unsigned)f2bf(a) | ((unsigned)f2bf(b) << 16);
}
DEVI unsigned pk_lo(float a, float b) {     // packed bf16 residuals
    float ra = a - bf2f(f2bf(a));
    float rb = b - bf2f(f2bf(b));
    return (unsigned)f2bf(ra) | ((unsigned)f2bf(rb) << 16);
}

// ---------------- setup: rowmap + qkv bias ----------------
// rowmap is the window-row <-> token-row bijection:
//   gather side:  xw[wrow] = x[rowmap[wrow]]      (roll(-3) + window partition)
//   scatter side: xa[rowmap[wrow]] = attn[wrow]   (window reverse + roll(+3))
__global__ void setup_misc(const float* __restrict__ qb, const float* __restrict__ vb,
                           float* __restrict__ qkvb, int* __restrict__ rowmap) {
    int idx = blockIdx.x * 256 + threadIdx.x;
    if (idx < 576) {
        float v = 0.f;
        if (idx < 192) v = qb[idx];
        else if (idx >= 384) v = vb[idx - 384];
        qkvb[idx] = v;
    }
    if (idx >= MROW) return;
    int n  = idx % NTOK, b_ = idx / NTOK;
    int b  = b_ >> 6,  wc = b_ & 63;
    int wh = wc >> 4,  ww = (wc >> 2) & 3, wd = wc & 3;
    int i0 = n / 49, r = n - i0 * 49, i1 = r / 7, i2 = r - i1 * 7;
    int h = wh * 7 + i0 + 3; if (h >= 28) h -= 28;
    int w = ww * 7 + i1 + 3; if (w >= 28) w -= 28;
    int d = wd * 7 + i2 + 3; if (d >= 28) d -= 28;
    rowmap[idx] = b * LTOK + (h * 28 + w) * 28 + d;
}

// split + zero-pad the four weight matrices into wsp (concatenated hi/lo planes)
__global__ void split_w(const float* __restrict__ qkv_w, const float* __restrict__ proj_w,
                        const float* __restrict__ fc1_w, const float* __restrict__ fc2_w,
                        u16* __restrict__ wsp) {
    int idx = blockIdx.x * 256 + threadIdx.x;
    if (idx >= 516096) return;
    const float* src; int Nn, K, baseH, baseL;
    if (idx < 122880)      { src = qkv_w;  Nn = 576; K = 192; baseH = WQKV_HI; baseL = WQKV_LO; }
    else if (idx < 172032) { idx -= 122880; src = proj_w; Nn = 192; K = 192; baseH = WPRJ_HI; baseL = WPRJ_LO; }
    else if (idx < 319488) { idx -= 172032; src = fc1_w;  Nn = 768; K = 192; baseH = WFC1_HI; baseL = WFC1_LO; }
    else                   { idx -= 319488; src = fc2_w;  Nn = 192; K = 768; baseH = WFC2_HI; baseL = WFC2_LO; }
    int r = idx / K, k = idx - r * K;
    float v = (r < Nn) ? src[r * K + k] : 0.f;
    u16 h = f2bf(v);
    wsp[baseH + idx] = h;
    wsp[baseL + idx] = f2bf(v - bf2f(h));
}

// ---------------- continuous position bias ----------------
DEVI float cpb_coord(int i) {
    float v = (float)(i - 6) * (8.f / 6.f);
    return copysignf(__log2f(fabsf(v) + 1.f) * (1.f / 3.f), v);
}

__global__ __launch_bounds__(64) void cpb_hidden(
    const float* __restrict__ w1, const float* __restrict__ b1,
    const float* __restrict__ w2, float* __restrict__ hb) {
    int t = blockIdx.x, lane = threadIdx.x;
    int a = t / 169, r = t - a * 169, bb = r / 13, cc = r - bb * 13;
    float t0 = cpb_coord(a), t1 = cpb_coord(bb), t2 = cpb_coord(cc);
    float acc[6] = {0.f, 0.f, 0.f, 0.f, 0.f, 0.f};
    for (int u = lane; u < 512; u += 64) {
        float h = fmaf(w1[u*3+0], t0, fmaf(w1[u*3+1], t1, fmaf(w1[u*3+2], t2, b1[u])));
        h = fmaxf(h, 0.f);
        #pragma unroll
        for (int e = 0; e < 6; ++e) acc[e] = fmaf(h, w2[e * 512 + u], acc[e]);
    }
    #pragma unroll
    for (int e = 0; e < 6; ++e)
        for (int off = 32; off; off >>= 1) acc[e] += __shfl_xor(acc[e], off);
    if (lane == 0) {
        #pragma unroll
        for (int e = 0; e < 6; ++e) hb[t * 6 + e] = acc[e];
    }
}

// rpbT[h][m][i] = 16*sigmoid(hb[rpi(query=i,key=m)][h])  (i fastest -> coalesced in attn)
__global__ void cpb_rpb(const float* __restrict__ hb, float* __restrict__ rpbT) {
    int idx = blockIdx.x * 256 + threadIdx.x;
    if (idx >= NTOK * NTOK) return;
    int m = idx / NTOK, i = idx - m * NTOK;
    int hi = i / 49, ri = i - hi * 49, wi = ri / 7, di = ri - wi * 7;
    int hm = m / 49, rm = m - hm * 49, wm = rm / 7, dm = rm - wm * 7;
    int rpi = (hi - hm + 6) * 169 + (wi - wm + 6) * 13 + (di - dm + 6);
    #pragma unroll
    for (int e = 0; e < 6; ++e) {
        float v = hb[rpi * 6 + e];
        rpbT[(size_t)e * NTOK * NTOK + idx] = 16.f / (1.f + __expf(-v));
    }
}

// ======================================================================
//  split-bf16 MFMA GEMM:  C[M,N] = A[M,K] * W[N,K]^T + bias
//  A is plain f32, split into hi/lo bf16 planes IN-STAGING (same bytes as f32).
//  W pre-split+padded to Np (multiple of 128).
//  BM=BN=128, BK=32, 4 waves in 2x2 grid, each wave 64x64 (16 MFMA tiles).
//  3-term product: Ah*Bh + Ah*Bl + Al*Bh  (~2^-17 relative error).
//  k-slot mapping sigma(g,j)=8g+j used consistently for A and B (relabel-safe).
//  C/D layout (HW-verified m89/m91): col=lane&15, row=4*(lane>>4)+j.
//  LDS: 16B-granule XOR swizzle (octet ^ (row&3)) on both write and read.
// ======================================================================
template<bool GELU_>
__global__ __launch_bounds__(256, 2) void gemm_mfma(
    const float* __restrict__ Af,
    const u16* __restrict__ Whi, const u16* __restrict__ Wlo,
    const float* __restrict__ bias, float* __restrict__ Cf,
    int Nn, int K,
    const int* __restrict__ inmap, const int* __restrict__ outmap) {
    __shared__ __align__(16) u16 sAh[4096], sAl[4096], sBh[4096], sBl[4096];
    const int tid = threadIdx.x;
    const int mbase = blockIdx.y * 128;
    const int nbase = blockIdx.x * 128;

    // --- staging: thread owns row sr, k-halves o0,o0+1 (16 consecutive k)
    const int sr = tid >> 1;
    const int o0 = (tid & 1) * 2;                 // octet index 0 or 2
    const int arow = inmap ? inmap[mbase + sr] : (mbase + sr);
    const float* pA = Af + (size_t)arow * K + o0 * 8;
    const u16* pBh = Whi + (size_t)(nbase + sr) * K + o0 * 8;
    const u16* pBl = Wlo + (size_t)(nbase + sr) * K + o0 * 8;
    const int off0 = sr * 32 + (((o0 + 0) * 8) ^ ((sr & 3) * 8));
    const int off1 = sr * 32 + (((o0 + 1) * 8) ^ ((sr & 3) * 8));

    // --- fragment read offsets
    const int lane = tid & 63, wv = tid >> 6;
    const int g = lane >> 4, q = lane & 15;
    const int wr = (wv >> 1) * 64, wc = (wv & 1) * 64;
    const int fx = (g * 8) ^ ((q & 3) * 8);
    int offs[4], offt[4];
    #pragma unroll
    for (int s = 0; s < 4; ++s) {
        offs[s] = (wr + s * 16 + q) * 32 + fx;
        offt[s] = (wc + s * 16 + q) * 32 + fx;
    }

    f32x4 acc[4][4];
    #pragma unroll
    for (int s = 0; s < 4; ++s)
        #pragma unroll
        for (int t = 0; t < 4; ++t) acc[s][t] = (f32x4){0.f, 0.f, 0.f, 0.f};

    float4 ra0 = *(const float4*)(pA + 0),  ra1 = *(const float4*)(pA + 4);
    float4 ra2 = *(const float4*)(pA + 8),  ra3 = *(const float4*)(pA + 12);
    float4 rbh0 = *(const float4*)pBh, rbh1 = *(const float4*)(pBh + 8);
    float4 rbl0 = *(const float4*)pBl, rbl1 = *(const float4*)(pBl + 8);

    for (int kt = 0; kt < K; kt += 32) {
        // A: convert f32 -> packed hi/lo bf16 octets, commit to LDS
        uint4 H0, L0, H1, L1;
        H0.x = pk_hi(ra0.x, ra0.y); H0.y = pk_hi(ra0.z, ra0.w);
        H0.z = pk_hi(ra1.x, ra1.y); H0.w = pk_hi(ra1.z, ra1.w);
        L0.x = pk_lo(ra0.x, ra0.y); L0.y = pk_lo(ra0.z, ra0.w);
        L0.z = pk_lo(ra1.x, ra1.y); L0.w = pk_lo(ra1.z, ra1.w);
        H1.x = pk_hi(ra2.x, ra2.y); H1.y = pk_hi(ra2.z, ra2.w);
        H1.z = pk_hi(ra3.x, ra3.y); H1.w = pk_hi(ra3.z, ra3.w);
        L1.x = pk_lo(ra2.x, ra2.y); L1.y = pk_lo(ra2.z, ra2.w);
        L1.z = pk_lo(ra3.x, ra3.y); L1.w = pk_lo(ra3.z, ra3.w);
        *(uint4*)&sAh[off0] = H0; *(uint4*)&sAl[off0] = L0;
        *(uint4*)&sAh[off1] = H1; *(uint4*)&sAl[off1] = L1;
        // B: pre-split planes, straight copy
        *(float4*)&sBh[off0] = rbh0; *(float4*)&sBh[off1] = rbh1;
        *(float4*)&sBl[off0] = rbl0; *(float4*)&sBl[off1] = rbl1;
        __syncthreads();
        if (kt + 32 < K) {                       // prefetch next K-tile
            int kn = kt + 32;
            ra0 = *(const float4*)(pA + kn);      ra1 = *(const float4*)(pA + kn + 4);
            ra2 = *(const float4*)(pA + kn + 8);  ra3 = *(const float4*)(pA + kn + 12);
            rbh0 = *(const float4*)(pBh + kn); rbh1 = *(const float4*)(pBh + kn + 8);
            rbl0 = *(const float4*)(pBl + kn); rbl1 = *(const float4*)(pBl + kn + 8);
        }
        bf16x8 ah[4], al[4], bh[4], bl[4];
        #pragma unroll
        for (int s = 0; s < 4; ++s) {
            ah[s] = *(const bf16x8*)&sAh[offs[s]];
            al[s] = *(const bf16x8*)&sAl[offs[s]];
            bh[s] = *(const bf16x8*)&sBh[offt[s]];
            bl[s] = *(const bf16x8*)&sBl[offt[s]];
        }
        #pragma unroll
        for (int s = 0; s < 4; ++s)
            #pragma unroll
            for (int t = 0; t < 4; ++t) {
                acc[s][t] = __builtin_amdgcn_mfma_f32_16x16x32_bf16(ah[s], bh[t], acc[s][t], 0, 0, 0);
                acc[s][t] = __builtin_amdgcn_mfma_f32_16x16x32_bf16(ah[s], bl[t], acc[s][t], 0, 0, 0);
                acc[s][t] = __builtin_amdgcn_mfma_f32_16x16x32_bf16(al[s], bh[t], acc[s][t], 0, 0, 0);
            }
        __syncthreads();
    }

    // --- epilogue: bias (+GELU), optional row scatter, f32 stores
    #pragma unroll
    for (int t = 0; t < 4; ++t) {
        const int gcol = nbase + wc + t * 16 + q;
        const bool ok = gcol < Nn;
        const float bv = ok ? bias[gcol] : 0.f;
        #pragma unroll
        for (int s = 0; s < 4; ++s) {
            #pragma unroll
            for (int j = 0; j < 4; ++j) {
                if (!ok) continue;
                const int grow = mbase + wr + s * 16 + g * 4 + j;
                float val = acc[s][t][j] + bv;
                if (GELU_) val = gelu_exact(val);
                const int orow = outmap ? outmap[grow] : grow;
                Cf[(size_t)orow * Nn + gcol] = val;
            }
        }
    }
}

// ---------------- fused window attention ----------------
// One block per (head, window); lane i owns query row i. K/V staged in LDS
// (XOR-swizzled float4 columns). Fixed softmax shift: s = cos*scale + rpb
// <= e + 16 < 19 (logit_scale in [0,1)), so exp(s-19) never overflows.
__global__ __launch_bounds__(384) void attn_kernel(
    const float* __restrict__ qkv, const float* __restrict__ rpbT,
    const float* __restrict__ logit_scale, float* __restrict__ out) {
    __shared__ float ks[TKV * 32];
    __shared__ float vs[TKV * 32];
    __shared__ int cnts[NTOK];

    const int tid  = threadIdx.x;
    const int head = blockIdx.x >> 7;
    const int b_   = blockIdx.x & 127;
    const int wc   = b_ & 63;
    const int wh = wc >> 4, ww = (wc >> 2) & 3, wd = wc & 3;

    const float scale = __expf(fminf(logit_scale[head], 4.6051701859880914f)); // ln(100)

    if (tid < NTOK) {
        int i0 = tid / 49, r = tid - i0 * 49, i1 = r / 7, i2 = r - i1 * 7;
        int r0 = (wh == 3) ? (i0 < 4 ? 1 : 2) : 0;   // bands [0,21)[21,25)[25,28)
        int r1 = (ww == 3) ? (i1 < 4 ? 1 : 2) : 0;
        int r2 = (wd == 3) ? (i2 < 4 ? 1 : 2) : 0;
        cnts[tid] = r0 * 9 + r1 * 3 + r2;
    }

    const int i = tid;
    float4 q[8], o[8];
    float S = 0.f;
    #pragma unroll
    for (int j = 0; j < 8; ++j) o[j] = make_float4(0.f, 0.f, 0.f, 0.f);

    if (i < NTOK) {
        const float4* qp = (const float4*)(qkv + ((size_t)(b_ * NTOK + i)) * 576 + head * 32);
        float ss = 0.f;
        #pragma unroll
        for (int j = 0; j < 8; ++j) { q[j] = qp[j]; ss += dot4(q[j], q[j]); }
        float inv = scale / fmaxf(sqrtf(ss), 1e-12f);
        #pragma unroll
        for (int j = 0; j < 8; ++j) { q[j].x *= inv; q[j].y *= inv; q[j].z *= inv; q[j].w *= inv; }
    }
    __syncthreads();
    int ci = (i < NTOK) ? cnts[i] : 0;
    const float* rbase = rpbT + (size_t)head * NTOK * NTOK + i;

    for (int m0 = 0; m0 < NTOK; m0 += TKV) {
        const int mcnt = min(TKV, NTOK - m0);
        __syncthreads();                       // previous tile fully consumed
        if (tid < mcnt) {
            int m = m0 + tid;
            const float4* kp = (const float4*)(qkv + ((size_t)(b_ * NTOK + m)) * 576 + 192 + head * 32);
            const float4* vp = (const float4*)(qkv + ((size_t)(b_ * NTOK + m)) * 576 + 384 + head * 32);
            float4 rr[8]; float ss = 0.f;
            #pragma unroll
            for (int j = 0; j < 8; ++j) { rr[j] = kp[j]; ss += dot4(rr[j], rr[j]); }
            float inv = 1.f / fmaxf(sqrtf(ss), 1e-12f);
            int sw = tid & 7;
            #pragma unroll
            for (int j = 0; j < 8; ++j) {
                float4 t = rr[j]; t.x *= inv; t.y *= inv; t.z *= inv; t.w *= inv;
                *(float4*)&ks[tid * 32 + ((j ^ sw) << 2)] = t;
            }
            #pragma unroll
            for (int j = 0; j < 8; ++j)
                *(float4*)&vs[tid * 32 + ((j ^ sw) << 2)] = vp[j];
        }
        __syncthreads();
        if (i < NTOK) {
            float rv_next = rbase[(size_t)m0 * NTOK];
            for (int mm = 0; mm < mcnt; ++mm) {
                const int m = m0 + mm;
                const int sw = mm & 7;
                const float* kr = &ks[mm * 32];
                float rv = rv_next;
                if (mm + 1 < mcnt) rv_next = rbase[(size_t)(m + 1) * NTOK];  // prefetch
                float sa = 0.f, sb = 0.f, sc = 0.f, sd = 0.f;
                #pragma unroll
                for (int j = 0; j < 8; ++j) {
                    float4 kk = *(const float4*)&kr[(j ^ sw) << 2];
                    sa = fmaf(q[j].x, kk.x, sa);
                    sb = fmaf(q[j].y, kk.y, sb);
                    sc = fmaf(q[j].z, kk.z, sc);
                    sd = fmaf(q[j].w, kk.w, sd);
                }
                float s = (sa + sb) + (sc + sd) + rv;
                s += (cnts[m] != ci) ? -100.f : 0.f;
                float p = __expf(s - 19.f);    // s <= 18.72 always
                S += p;
                const float* vr = &vs[mm * 32];
                #pragma unroll
                for (int j = 0; j < 8; ++j) {
                    float4 vv = *(const float4*)&vr[(j ^ sw) << 2];
                    o[j].x = fmaf(p, vv.x, o[j].x);
                    o[j].y = fmaf(p, vv.y, o[j].y);
                    o[j].z = fmaf(p, vv.z, o[j].z);
                    o[j].w = fmaf(p, vv.w, o[j].w);
                }
            }
        }
    }

    if (i < NTOK) {
        float invS = 1.f / S;
        float4* op = (float4*)(out + ((size_t)(b_ * NTOK + i)) * CDIM + head * 32);
        #pragma unroll
        for (int j = 0; j < 8; ++j) {
            float4 t = o[j];
            t.x *= invS; t.y *= invS; t.z *= invS; t.w *= invS;
            op[j] = t;
        }
    }
}

// ---------------- residual + LayerNorm (1 wave per token) ----------------
__global__ __launch_bounds__(256) void ln_residual(
    const float* __restrict__ base, const float* __restrict__ val,
    const float* __restrict__ g, const float* __restrict__ bt,
    float* __restrict__ out) {
    int gw = (blockIdx.x * 256 + threadIdx.x) >> 6;
    int lane = threadIdx.x & 63;
    if (gw >= MROW) return;
    const float* v = val + (size_t)gw * CDIM;
    float x0 = v[lane], x1 = v[lane + 64], x2 = v[lane + 128];
    float s = x0 + x1 + x2;
    for (int off = 32; off; off >>= 1) s += __shfl_xor(s, off);
    float mean = s * (1.f / 192.f);
    float d0 = x0 - mean, d1 = x1 - mean, d2 = x2 - mean;
    float vv = d0 * d0 + d1 * d1 + d2 * d2;
    for (int off = 32; off; off >>= 1) vv += __shfl_xor(vv, off);
    float inv = rsqrtf(vv * (1.f / 192.f) + 1e-5f);
    const float* bp = base + (size_t)gw * CDIM;
    float* op = out + (size_t)gw * CDIM;
    op[lane]       = bp[lane]       + d0 * inv * g[lane]       + bt[lane];
    op[lane + 64]  = bp[lane + 64]  + d1 * inv * g[lane + 64]  + bt[lane + 64];
    op[lane + 128] = bp[lane + 128] + d2 * inv * g[lane + 128] + bt[lane + 128];
}

// ---------------- launch ----------------
extern "C" void kernel_launch(void* const* d_in, const int* in_sizes, int n_in,
                              void* d_out, int out_size, void* d_ws, size_t ws_size,
                              hipStream_t stream) {
    const float* x           = (const float*)d_in[0];
    const float* qkv_w       = (const float*)d_in[1];
    const float* q_bias      = (const float*)d_in[2];
    const float* v_bias      = (const float*)d_in[3];
    const float* logit_scale = (const float*)d_in[4];
    const float* cpb_w1      = (const float*)d_in[5];
    const float* cpb_b1      = (const float*)d_in[6];
    const float* cpb_w2      = (const float*)d_in[7];
    const float* proj_w      = (const float*)d_in[8];
    const float* proj_b      = (const float*)d_in[9];
    const float* norm1_g     = (const float*)d_in[10];
    const float* norm1_b     = (const float*)d_in[11];
    const float* fc1_w       = (const float*)d_in[12];
    const float* fc1_b       = (const float*)d_in[13];
    const float* fc2_w       = (const float*)d_in[14];
    const float* fc2_b       = (const float*)d_in[15];
    const float* norm2_g     = (const float*)d_in[16];
    const float* norm2_b     = (const float*)d_in[17];

    char* ws = (char*)d_ws;
    float* attnb = (float*)(ws + OFF_ATTN);   // attn out (window order); later fc2 out
    float* qkv   = (float*)(ws + OFF_QKV);    // qkv f32; region later reused as h
    float* hbuf  = qkv;
    float* mbuf  = attnb;
    float* xa    = (float*)(ws + OFF_XA);
    float* x1    = (float*)(ws + OFF_X1);
    float* rpbT  = (float*)(ws + OFF_RPBT);
    float* hb    = (float*)(ws + OFF_HB);
    float* qkvb  = (float*)(ws + OFF_QKVB);
    int*   rmap  = (int*)(ws + OFF_RMAP);
    u16*   wsp   = (u16*)(ws + OFF_WSP);

    setup_misc<<<(MROW + 255) / 256, 256, 0, stream>>>(q_bias, v_bias, qkvb, rmap);
    split_w<<<(516096 + 255) / 256, 256, 0, stream>>>(qkv_w, proj_w, fc1_w, fc2_w, wsp);
    cpb_hidden<<<2197, 64, 0, stream>>>(cpb_w1, cpb_b1, cpb_w2, hb);
    cpb_rpb<<<(NTOK * NTOK + 255) / 256, 256, 0, stream>>>(hb, rpbT);

    // qkv: reads x f32 through the gather map (roll + window partition fused)
    gemm_mfma<false><<<dim3(5, 343), 256, 0, stream>>>(
        x, wsp + WQKV_HI, wsp + WQKV_LO, qkvb, qkv, 576, 192, rmap, nullptr);

    attn_kernel<<<NHEAD * 128, 384, 0, stream>>>(qkv, rpbT, logit_scale, attnb);

    // proj: scatters through the same map (window reverse + roll fused)
    gemm_mfma<false><<<dim3(2, 343), 256, 0, stream>>>(
        attnb, wsp + WPRJ_HI, wsp + WPRJ_LO, proj_b, xa, 192, 192, nullptr, rmap);

    ln_residual<<<MROW / 4, 256, 0, stream>>>(x, xa, norm1_g, norm1_b, x1);

    gemm_mfma<true><<<dim3(6, 343), 256, 0, stream>>>(
        x1, wsp + WFC1_HI, wsp + WFC1_LO, fc1_b, hbuf, 768, 192, nullptr, nullptr);

    gemm_mfma<false><<<dim3(2, 343), 256, 0, stream>>>(
        hbuf, wsp + WFC2_HI, wsp + WFC2_LO, fc2_b, mbuf, 192, 768, nullptr, nullptr);

    ln_residual<<<MROW / 4, 256, 0, stream>>>(x1, mbuf, norm2_g, norm2_b, (float*)d_out);
}

// Round 9
// 522.270 us; speedup vs baseline: 1.6075x; 1.6075x over previous
//
#include <hip/hip_runtime.h>

#define DEVI static __device__ __forceinline__
typedef unsigned short u16;
typedef short bf16x8 __attribute__((ext_vector_type(8)));
typedef float f32x4 __attribute__((ext_vector_type(4)));

// ---------------- problem constants ----------------
constexpr int LTOK  = 21952;          // 28^3
constexpr int CDIM  = 192;
constexpr int NHEAD = 6;
constexpr int NTOK  = 343;            // 7^3 tokens per window
constexpr int MROW  = 43904;          // 2 * 21952 = 128 * 343

// ---------------- workspace layout (bytes) ----------------
constexpr size_t OFF_ATTN = 0;                     // attn out f32 [M,192]; later fc2 out
constexpr size_t OFF_QKV  = 33718272;              // qkv f32 [M,576]; later h [M,768]
constexpr size_t OFF_XA   = 168591360;             // proj out f32, token order
constexpr size_t OFF_X1   = 202309632;             // x1 f32
constexpr size_t OFF_RPBT = 236027904;             // rpbT [6][352][352] f32 (padded)
constexpr size_t OFF_HB   = 239002624;             // hb [2197][6] f32
constexpr size_t OFF_QKVB = 239055872;             // qkv bias [576] f32
constexpr size_t OFF_RMAP = 239059968;             // rowmap [43904] int
constexpr size_t OFF_WSP  = 239235584;             // split+padded weights (u16)
// total ~= 241,299,968 bytes

// split-weight sub-offsets (u16 element units within WSP)
constexpr int WQKV_HI = 0,      WQKV_LO = 122880;   // Np=640 K=192
constexpr int WPRJ_HI = 245760, WPRJ_LO = 294912;   // Np=256 K=192
constexpr int WFC1_HI = 344064, WFC1_LO = 491520;   // Np=768 K=192
constexpr int WFC2_HI = 638976, WFC2_LO = 835584;   // Np=256 K=768

// ---------------- small helpers ----------------
DEVI float dot4(const float4 a, const float4 b) {
    return a.x*b.x + a.y*b.y + a.z*b.z + a.w*b.w;
}
DEVI float gelu_exact(float x) {
    return 0.5f * x * (1.f + erff(x * 0.70710678118654752440f));
}
DEVI u16 f2bf(float f) {                    // round-to-nearest-even f32 -> bf16
    unsigned u = __float_as_uint(f);
    u += 0x7fffu + ((u >> 16) & 1u);
    return (u16)(u >> 16);
}
DEVI float bf2f(u16 h) { return __uint_as_float(((unsigned)h) << 16); }
DEVI unsigned pk_hi(float a, float b) {     // packed bf16 hi parts
    return (unsigned)f2bf(a) | ((unsigned)f2bf(b) << 16);
}
DEVI unsigned pk_lo(float a, float b) {     // packed bf16 residuals
    float ra = a - bf2f(f2bf(a));
    float rb = b - bf2f(f2bf(b));
    return (unsigned)f2bf(ra) | ((unsigned)f2bf(rb) << 16);
}

// ---------------- setup: rowmap + qkv bias ----------------
__global__ void setup_misc(const float* __restrict__ qb, const float* __restrict__ vb,
                           float* __restrict__ qkvb, int* __restrict__ rowmap) {
    int idx = blockIdx.x * 256 + threadIdx.x;
    if (idx < 576) {
        float v = 0.f;
        if (idx < 192) v = qb[idx];
        else if (idx >= 384) v = vb[idx - 384];
        qkvb[idx] = v;
    }
    if (idx >= MROW) return;
    int n  = idx % NTOK, b_ = idx / NTOK;
    int b  = b_ >> 6,  wc = b_ & 63;
    int wh = wc >> 4,  ww = (wc >> 2) & 3, wd = wc & 3;
    int i0 = n / 49, r = n - i0 * 49, i1 = r / 7, i2 = r - i1 * 7;
    int h = wh * 7 + i0 + 3; if (h >= 28) h -= 28;
    int w = ww * 7 + i1 + 3; if (w >= 28) w -= 28;
    int d = wd * 7 + i2 + 3; if (d >= 28) d -= 28;
    rowmap[idx] = b * LTOK + (h * 28 + w) * 28 + d;
}

// split + zero-pad the four weight matrices into wsp
__global__ void split_w(const float* __restrict__ qkv_w, const float* __restrict__ proj_w,
                        const float* __restrict__ fc1_w, const float* __restrict__ fc2_w,
                        u16* __restrict__ wsp) {
    int idx = blockIdx.x * 256 + threadIdx.x;
    if (idx >= 516096) return;
    const float* src; int Nn, K, baseH, baseL;
    if (idx < 122880)      { src = qkv_w;  Nn = 576; K = 192; baseH = WQKV_HI; baseL = WQKV_LO; }
    else if (idx < 172032) { idx -= 122880; src = proj_w; Nn = 192; K = 192; baseH = WPRJ_HI; baseL = WPRJ_LO; }
    else if (idx < 319488) { idx -= 172032; src = fc1_w;  Nn = 768; K = 192; baseH = WFC1_HI; baseL = WFC1_LO; }
    else                   { idx -= 319488; src = fc2_w;  Nn = 192; K = 768; baseH = WFC2_HI; baseL = WFC2_LO; }
    int r = idx / K, k = idx - r * K;
    float v = (r < Nn) ? src[r * K + k] : 0.f;
    u16 h = f2bf(v);
    wsp[baseH + idx] = h;
    wsp[baseL + idx] = f2bf(v - bf2f(h));
}

// ---------------- continuous position bias ----------------
DEVI float cpb_coord(int i) {
    float v = (float)(i - 6) * (8.f / 6.f);
    return copysignf(__log2f(fabsf(v) + 1.f) * (1.f / 3.f), v);
}

__global__ __launch_bounds__(64) void cpb_hidden(
    const float* __restrict__ w1, const float* __restrict__ b1,
    const float* __restrict__ w2, float* __restrict__ hb) {
    int t = blockIdx.x, lane = threadIdx.x;
    int a = t / 169, r = t - a * 169, bb = r / 13, cc = r - bb * 13;
    float t0 = cpb_coord(a), t1 = cpb_coord(bb), t2 = cpb_coord(cc);
    float acc[6] = {0.f, 0.f, 0.f, 0.f, 0.f, 0.f};
    for (int u = lane; u < 512; u += 64) {
        float h = fmaf(w1[u*3+0], t0, fmaf(w1[u*3+1], t1, fmaf(w1[u*3+2], t2, b1[u])));
        h = fmaxf(h, 0.f);
        #pragma unroll
        for (int e = 0; e < 6; ++e) acc[e] = fmaf(h, w2[e * 512 + u], acc[e]);
    }
    #pragma unroll
    for (int e = 0; e < 6; ++e)
        for (int off = 32; off; off >>= 1) acc[e] += __shfl_xor(acc[e], off);
    if (lane == 0) {
        #pragma unroll
        for (int e = 0; e < 6; ++e) hb[t * 6 + e] = acc[e];
    }
}

// rpbT[h][m=key][i=query], padded to 352x352 so attention float4 reads stay in-bounds
__global__ void cpb_rpb(const float* __restrict__ hb, float* __restrict__ rpbT) {
    int idx = blockIdx.x * 256 + threadIdx.x;
    if (idx >= 352 * 352) return;
    int m = idx / 352, i = idx - m * 352;
    int ic = min(i, 342), mc = min(m, 342);
    int hi = ic / 49, ri = ic - hi * 49, wi = ri / 7, di = ri - wi * 7;
    int hm = mc / 49, rm = mc - hm * 49, wm = rm / 7, dm = rm - wm * 7;
    int rpi = (hi - hm + 6) * 169 + (wi - wm + 6) * 13 + (di - dm + 6);
    #pragma unroll
    for (int e = 0; e < 6; ++e) {
        float v = hb[rpi * 6 + e];
        rpbT[(size_t)e * 123904 + idx] = 16.f / (1.f + __expf(-v));
    }
}

// ======================================================================
//  split-bf16 MFMA GEMM (unchanged from passing round-5 kernel)
// ======================================================================
template<bool GELU_>
__global__ __launch_bounds__(256, 2) void gemm_mfma(
    const float* __restrict__ Af,
    const u16* __restrict__ Whi, const u16* __restrict__ Wlo,
    const float* __restrict__ bias, float* __restrict__ Cf,
    int Nn, int K,
    const int* __restrict__ inmap, const int* __restrict__ outmap) {
    __shared__ __align__(16) u16 sAh[4096], sAl[4096], sBh[4096], sBl[4096];
    const int tid = threadIdx.x;
    const int mbase = blockIdx.y * 128;
    const int nbase = blockIdx.x * 128;

    const int sr = tid >> 1;
    const int o0 = (tid & 1) * 2;
    const int arow = inmap ? inmap[mbase + sr] : (mbase + sr);
    const float* pA = Af + (size_t)arow * K + o0 * 8;
    const u16* pBh = Whi + (size_t)(nbase + sr) * K + o0 * 8;
    const u16* pBl = Wlo + (size_t)(nbase + sr) * K + o0 * 8;
    const int off0 = sr * 32 + (((o0 + 0) * 8) ^ ((sr & 3) * 8));
    const int off1 = sr * 32 + (((o0 + 1) * 8) ^ ((sr & 3) * 8));

    const int lane = tid & 63, wv = tid >> 6;
    const int g = lane >> 4, q = lane & 15;
    const int wr = (wv >> 1) * 64, wc = (wv & 1) * 64;
    const int fx = (g * 8) ^ ((q & 3) * 8);
    int offs[4], offt[4];
    #pragma unroll
    for (int s = 0; s < 4; ++s) {
        offs[s] = (wr + s * 16 + q) * 32 + fx;
        offt[s] = (wc + s * 16 + q) * 32 + fx;
    }

    f32x4 acc[4][4];
    #pragma unroll
    for (int s = 0; s < 4; ++s)
        #pragma unroll
        for (int t = 0; t < 4; ++t) acc[s][t] = (f32x4){0.f, 0.f, 0.f, 0.f};

    float4 ra0 = *(const float4*)(pA + 0),  ra1 = *(const float4*)(pA + 4);
    float4 ra2 = *(const float4*)(pA + 8),  ra3 = *(const float4*)(pA + 12);
    float4 rbh0 = *(const float4*)pBh, rbh1 = *(const float4*)(pBh + 8);
    float4 rbl0 = *(const float4*)pBl, rbl1 = *(const float4*)(pBl + 8);

    for (int kt = 0; kt < K; kt += 32) {
        uint4 H0, L0, H1, L1;
        H0.x = pk_hi(ra0.x, ra0.y); H0.y = pk_hi(ra0.z, ra0.w);
        H0.z = pk_hi(ra1.x, ra1.y); H0.w = pk_hi(ra1.z, ra1.w);
        L0.x = pk_lo(ra0.x, ra0.y); L0.y = pk_lo(ra0.z, ra0.w);
        L0.z = pk_lo(ra1.x, ra1.y); L0.w = pk_lo(ra1.z, ra1.w);
        H1.x = pk_hi(ra2.x, ra2.y); H1.y = pk_hi(ra2.z, ra2.w);
        H1.z = pk_hi(ra3.x, ra3.y); H1.w = pk_hi(ra3.z, ra3.w);
        L1.x = pk_lo(ra2.x, ra2.y); L1.y = pk_lo(ra2.z, ra2.w);
        L1.z = pk_lo(ra3.x, ra3.y); L1.w = pk_lo(ra3.z, ra3.w);
        *(uint4*)&sAh[off0] = H0; *(uint4*)&sAl[off0] = L0;
        *(uint4*)&sAh[off1] = H1; *(uint4*)&sAl[off1] = L1;
        *(float4*)&sBh[off0] = rbh0; *(float4*)&sBh[off1] = rbh1;
        *(float4*)&sBl[off0] = rbl0; *(float4*)&sBl[off1] = rbl1;
        __syncthreads();
        if (kt + 32 < K) {
            int kn = kt + 32;
            ra0 = *(const float4*)(pA + kn);      ra1 = *(const float4*)(pA + kn + 4);
            ra2 = *(const float4*)(pA + kn + 8);  ra3 = *(const float4*)(pA + kn + 12);
            rbh0 = *(const float4*)(pBh + kn); rbh1 = *(const float4*)(pBh + kn + 8);
            rbl0 = *(const float4*)(pBl + kn); rbl1 = *(const float4*)(pBl + kn + 8);
        }
        bf16x8 ah[4], al[4], bh[4], bl[4];
        #pragma unroll
        for (int s = 0; s < 4; ++s) {
            ah[s] = *(const bf16x8*)&sAh[offs[s]];
            al[s] = *(const bf16x8*)&sAl[offs[s]];
            bh[s] = *(const bf16x8*)&sBh[offt[s]];
            bl[s] = *(const bf16x8*)&sBl[offt[s]];
        }
        #pragma unroll
        for (int s = 0; s < 4; ++s)
            #pragma unroll
            for (int t = 0; t < 4; ++t) {
                acc[s][t] = __builtin_amdgcn_mfma_f32_16x16x32_bf16(ah[s], bh[t], acc[s][t], 0, 0, 0);
                acc[s][t] = __builtin_amdgcn_mfma_f32_16x16x32_bf16(ah[s], bl[t], acc[s][t], 0, 0, 0);
                acc[s][t] = __builtin_amdgcn_mfma_f32_16x16x32_bf16(al[s], bh[t], acc[s][t], 0, 0, 0);
            }
        __syncthreads();
    }

    #pragma unroll
    for (int t = 0; t < 4; ++t) {
        const int gcol = nbase + wc + t * 16 + q;
        const bool ok = gcol < Nn;
        const float bv = ok ? bias[gcol] : 0.f;
        #pragma unroll
        for (int s = 0; s < 4; ++s) {
            #pragma unroll
            for (int j = 0; j < 4; ++j) {
                if (!ok) continue;
                const int grow = mbase + wr + s * 16 + g * 4 + j;
                float val = acc[s][t][j] + bv;
                if (GELU_) val = gelu_exact(val);
                const int orow = outmap ? outmap[grow] : grow;
                Cf[(size_t)orow * Nn + gcol] = val;
            }
        }
    }
}

// ======================================================================
//  fused MFMA window attention. One block per (head, window), 8 waves.
//  Q/K normalized + split bf16 in LDS (same frag pattern/swizzle as GEMM);
//  V transposed [32][384] split (stride 384: swizzled octet pos in [0,48)
//  must stay in-row -- 352 overflowed and corrupted neighbor rows);
//  S and PV are 3-term split MFMA; softmax uses fixed shift
//  (s = cos*scale + rpb <= e+16 < 19), no max pass.
//  Padded keys: zeroed K/V rows + sentinel region id -> p = exp(-119) = 0.
// ======================================================================
__global__ __launch_bounds__(512, 1) void attn_mfma(
    const float* __restrict__ qkv, const float* __restrict__ rpbT,
    const float* __restrict__ logit_scale, float* __restrict__ out) {
    __shared__ __align__(16) u16 sKh[352 * 32], sKl[352 * 32];   // Q staged here first
    __shared__ __align__(16) u16 sVh[32 * 384], sVl[32 * 384];   // V transposed, padded stride
    __shared__ __align__(16) u16 sPh[8][512], sPl[8][512];       // per-wave P tile [16][32]
    __shared__ int scnt[352];

    const int tid  = threadIdx.x;
    const int head = blockIdx.x >> 7;
    const int b_   = blockIdx.x & 127;
    const int wcd  = b_ & 63;
    const int wh = wcd >> 4, ww = (wcd >> 2) & 3, wd = wcd & 3;
    const int lane = tid & 63, wv = tid >> 6;
    const int lw = lane & 15, g = lane >> 4;
    const int fx = ((g ^ (lw & 3)) << 3);
    const int wbase = (wv < 6) ? wv * 3 : 18 + (wv - 6) * 2;   // 22 M-tiles: {3,3,3,3,3,3,2,2}
    const int mcnt  = (wv < 6) ? 3 : 2;

    const float scale = __expf(fminf(logit_scale[head], 4.6051701859880914f)); // ln(100)

    // ---- phase 1: stage Q (normalized * scale, split, swizzled) ----
    if (tid < 352) {
        float v[32];
        #pragma unroll
        for (int k = 0; k < 32; ++k) v[k] = 0.f;
        if (tid < 343) {
            const float4* p = (const float4*)(qkv + ((size_t)(b_ * 343 + tid)) * 576 + head * 32);
            float ss = 0.f;
            #pragma unroll
            for (int o = 0; o < 8; ++o) {
                float4 t = p[o];
                v[o*4+0] = t.x; v[o*4+1] = t.y; v[o*4+2] = t.z; v[o*4+3] = t.w;
                ss += dot4(t, t);
            }
            float inv = scale / fmaxf(sqrtf(ss), 1e-12f);
            #pragma unroll
            for (int k = 0; k < 32; ++k) v[k] *= inv;
        }
        #pragma unroll
        for (int o = 0; o < 4; ++o) {
            uint4 H, L;
            H.x = pk_hi(v[o*8+0], v[o*8+1]); L.x = pk_lo(v[o*8+0], v[o*8+1]);
            H.y = pk_hi(v[o*8+2], v[o*8+3]); L.y = pk_lo(v[o*8+2], v[o*8+3]);
            H.z = pk_hi(v[o*8+4], v[o*8+5]); L.z = pk_lo(v[o*8+4], v[o*8+5]);
            H.w = pk_hi(v[o*8+6], v[o*8+7]); L.w = pk_lo(v[o*8+6], v[o*8+7]);
            int so = tid * 32 + ((o ^ (tid & 3)) << 3);
            *(uint4*)&sKh[so] = H;
            *(uint4*)&sKl[so] = L;
        }
    }
    __syncthreads();

    // ---- phase 2: pull Q A-fragments to registers ----
    bf16x8 qh[3], ql[3];
    #pragma unroll
    for (int mt = 0; mt < 3; ++mt) {
        if (mt < mcnt) {
            int r = (wbase + mt) * 16 + lw;
            qh[mt] = *(const bf16x8*)&sKh[r * 32 + fx];
            ql[mt] = *(const bf16x8*)&sKl[r * 32 + fx];
        }
    }
    __syncthreads();

    // ---- phase 3: stage K (normalized), V^T, region ids ----
    if (tid < 352) {
        float v[32];
        #pragma unroll
        for (int k = 0; k < 32; ++k) v[k] = 0.f;
        if (tid < 343) {
            const float4* p = (const float4*)(qkv + ((size_t)(b_ * 343 + tid)) * 576 + 192 + head * 32);
            float ss = 0.f;
            #pragma unroll
            for (int o = 0; o < 8; ++o) {
                float4 t = p[o];
                v[o*4+0] = t.x; v[o*4+1] = t.y; v[o*4+2] = t.z; v[o*4+3] = t.w;
                ss += dot4(t, t);
            }
            float inv = 1.f / fmaxf(sqrtf(ss), 1e-12f);
            #pragma unroll
            for (int k = 0; k < 32; ++k) v[k] *= inv;
        }
        #pragma unroll
        for (int o = 0; o < 4; ++o) {
            uint4 H, L;
            H.x = pk_hi(v[o*8+0], v[o*8+1]); L.x = pk_lo(v[o*8+0], v[o*8+1]);
            H.y = pk_hi(v[o*8+2], v[o*8+3]); L.y = pk_lo(v[o*8+2], v[o*8+3]);
            H.z = pk_hi(v[o*8+4], v[o*8+5]); L.z = pk_lo(v[o*8+4], v[o*8+5]);
            H.w = pk_hi(v[o*8+6], v[o*8+7]); L.w = pk_lo(v[o*8+6], v[o*8+7]);
            int so = tid * 32 + ((o ^ (tid & 3)) << 3);
            *(uint4*)&sKh[so] = H;
            *(uint4*)&sKl[so] = L;
        }
        // V transposed (zeros for pad keys)
        float vv[32];
        #pragma unroll
        for (int k = 0; k < 32; ++k) vv[k] = 0.f;
        if (tid < 343) {
            const float4* p = (const float4*)(qkv + ((size_t)(b_ * 343 + tid)) * 576 + 384 + head * 32);
            #pragma unroll
            for (int o = 0; o < 8; ++o) {
                float4 t = p[o];
                vv[o*4+0] = t.x; vv[o*4+1] = t.y; vv[o*4+2] = t.z; vv[o*4+3] = t.w;
            }
        }
        const int ko = tid >> 3, kw = tid & 7;
        #pragma unroll
        for (int d = 0; d < 32; ++d) {
            u16 h = f2bf(vv[d]);
            u16 l = f2bf(vv[d] - bf2f(h));
            int ad = d * 384 + ((ko ^ (d & 7)) << 3) + kw;   // pos in [0,48) -> in-row
            sVh[ad] = h; sVl[ad] = l;
        }
        // region ids
        int c = 127;
        if (tid < 343) {
            int i0 = tid / 49, r = tid - i0 * 49, i1 = r / 7, i2 = r - i1 * 7;
            int r0 = (wh == 3) ? (i0 < 4 ? 1 : 2) : 0;
            int r1 = (ww == 3) ? (i1 < 4 ? 1 : 2) : 0;
            int r2 = (wd == 3) ? (i2 < 4 ? 1 : 2) : 0;
            c = r0 * 9 + r1 * 3 + r2;
        }
        scnt[tid] = c;
    }
    __syncthreads();

    // per-M-tile query region ids
    int cq[3][4];
    #pragma unroll
    for (int mt = 0; mt < 3; ++mt)
        if (mt < mcnt) {
            #pragma unroll
            for (int j = 0; j < 4; ++j)
                cq[mt][j] = scnt[(wbase + mt) * 16 + 4 * g + j];
        }

    f32x4 oacc[3][2];
    float dS[3][4];
    #pragma unroll
    for (int mt = 0; mt < 3; ++mt) {
        oacc[mt][0] = (f32x4){0.f, 0.f, 0.f, 0.f};
        oacc[mt][1] = (f32x4){0.f, 0.f, 0.f, 0.f};
        #pragma unroll
        for (int j = 0; j < 4; ++j) dS[mt][j] = 0.f;
    }
    const float* rbp = rpbT + (size_t)head * 123904;

    // ---- main loop: 11 key-chunks of 32 (no barriers; per-wave P buffers) ----
    for (int ch = 0; ch < 11; ++ch) {
        const int kb = ch * 32;
        bf16x8 kh0 = *(const bf16x8*)&sKh[(kb + lw) * 32 + fx];
        bf16x8 kl0 = *(const bf16x8*)&sKl[(kb + lw) * 32 + fx];
        bf16x8 kh1 = *(const bf16x8*)&sKh[(kb + 16 + lw) * 32 + fx];
        bf16x8 kl1 = *(const bf16x8*)&sKl[(kb + 16 + lw) * 32 + fx];
        const int vo = ((ch * 4 + g) ^ (lw & 7)) << 3;
        bf16x8 vh0 = *(const bf16x8*)&sVh[lw * 384 + vo];
        bf16x8 vl0 = *(const bf16x8*)&sVl[lw * 384 + vo];
        bf16x8 vh1 = *(const bf16x8*)&sVh[(16 + lw) * 384 + vo];
        bf16x8 vl1 = *(const bf16x8*)&sVl[(16 + lw) * 384 + vo];
        const int ck0 = scnt[kb + lw];
        const int ck1 = scnt[kb + 16 + lw];

        #pragma unroll
        for (int mt = 0; mt < 3; ++mt) {
            if (mt >= mcnt) continue;
            const int mb = (wbase + mt) * 16;
            f32x4 s0 = (f32x4){0.f, 0.f, 0.f, 0.f};
            f32x4 s1 = (f32x4){0.f, 0.f, 0.f, 0.f};
            s0 = __builtin_amdgcn_mfma_f32_16x16x32_bf16(qh[mt], kh0, s0, 0, 0, 0);
            s0 = __builtin_amdgcn_mfma_f32_16x16x32_bf16(qh[mt], kl0, s0, 0, 0, 0);
            s0 = __builtin_amdgcn_mfma_f32_16x16x32_bf16(ql[mt], kh0, s0, 0, 0, 0);
            s1 = __builtin_amdgcn_mfma_f32_16x16x32_bf16(qh[mt], kh1, s1, 0, 0, 0);
            s1 = __builtin_amdgcn_mfma_f32_16x16x32_bf16(qh[mt], kl1, s1, 0, 0, 0);
            s1 = __builtin_amdgcn_mfma_f32_16x16x32_bf16(ql[mt], kh1, s1, 0, 0, 0);
            float4 rv0 = *(const float4*)&rbp[(size_t)(kb + lw) * 352 + mb + 4 * g];
            float4 rv1 = *(const float4*)&rbp[(size_t)(kb + 16 + lw) * 352 + mb + 4 * g];
            const float* r0p = (const float*)&rv0;
            const float* r1p = (const float*)&rv1;
            float p0[4], p1[4];
            #pragma unroll
            for (int j = 0; j < 4; ++j) {
                float a0 = s0[j] + r0p[j] + ((ck0 != cq[mt][j]) ? -100.f : 0.f);
                float a1 = s1[j] + r1p[j] + ((ck1 != cq[mt][j]) ? -100.f : 0.f);
                p0[j] = __expf(a0 - 19.f);
                p1[j] = __expf(a1 - 19.f);
                dS[mt][j] += p0[j] + p1[j];
            }
            // P -> LDS (split, swizzled [q][key] tile)
            const int po = lw >> 3, pw = lw & 7;
            #pragma unroll
            for (int j = 0; j < 4; ++j) {
                int base = (4 * g + j) * 32 + pw;
                int a0 = base + ((po ^ j) << 3);
                int a1 = base + (((2 + po) ^ j) << 3);
                u16 h0 = f2bf(p0[j]);
                sPh[wv][a0] = h0; sPl[wv][a0] = f2bf(p0[j] - bf2f(h0));
                u16 h1 = f2bf(p1[j]);
                sPh[wv][a1] = h1; sPl[wv][a1] = f2bf(p1[j] - bf2f(h1));
            }
            bf16x8 pah = *(const bf16x8*)&sPh[wv][lw * 32 + fx];
            bf16x8 pal = *(const bf16x8*)&sPl[wv][lw * 32 + fx];
            oacc[mt][0] = __builtin_amdgcn_mfma_f32_16x16x32_bf16(pah, vh0, oacc[mt][0], 0, 0, 0);
            oacc[mt][0] = __builtin_amdgcn_mfma_f32_16x16x32_bf16(pah, vl0, oacc[mt][0], 0, 0, 0);
            oacc[mt][0] = __builtin_amdgcn_mfma_f32_16x16x32_bf16(pal, vh0, oacc[mt][0], 0, 0, 0);
            oacc[mt][1] = __builtin_amdgcn_mfma_f32_16x16x32_bf16(pah, vh1, oacc[mt][1], 0, 0, 0);
            oacc[mt][1] = __builtin_amdgcn_mfma_f32_16x16x32_bf16(pah, vl1, oacc[mt][1], 0, 0, 0);
            oacc[mt][1] = __builtin_amdgcn_mfma_f32_16x16x32_bf16(pal, vh1, oacc[mt][1], 0, 0, 0);
        }
    }

    // ---- epilogue: denominator reduce + normalized store ----
    #pragma unroll
    for (int mt = 0; mt < 3; ++mt) {
        if (mt >= mcnt) continue;
        float inv[4];
        #pragma unroll
        for (int j = 0; j < 4; ++j) {
            float s = dS[mt][j];
            s += __shfl_xor(s, 1);
            s += __shfl_xor(s, 2);
            s += __shfl_xor(s, 4);
            s += __shfl_xor(s, 8);
            inv[j] = 1.f / s;
        }
        const int mb = (wbase + mt) * 16;
        #pragma unroll
        for (int j = 0; j < 4; ++j) {
            int grow = mb + 4 * g + j;
            if (grow < 343) {
                size_t ro = ((size_t)(b_ * 343 + grow)) * 192 + head * 32;
                out[ro + lw]      = oacc[mt][0][j] * inv[j];
                out[ro + 16 + lw] = oacc[mt][1][j] * inv[j];
            }
        }
    }
}

// ---------------- residual + LayerNorm (1 wave per token) ----------------
__global__ __launch_bounds__(256) void ln_residual(
    const float* __restrict__ base, const float* __restrict__ val,
    const float* __restrict__ g, const float* __restrict__ bt,
    float* __restrict__ out) {
    int gw = (blockIdx.x * 256 + threadIdx.x) >> 6;
    int lane = threadIdx.x & 63;
    if (gw >= MROW) return;
    const float* v = val + (size_t)gw * CDIM;
    float x0 = v[lane], x1 = v[lane + 64], x2 = v[lane + 128];
    float s = x0 + x1 + x2;
    for (int off = 32; off; off >>= 1) s += __shfl_xor(s, off);
    float mean = s * (1.f / 192.f);
    float d0 = x0 - mean, d1 = x1 - mean, d2 = x2 - mean;
    float vv = d0 * d0 + d1 * d1 + d2 * d2;
    for (int off = 32; off; off >>= 1) vv += __shfl_xor(vv, off);
    float inv = rsqrtf(vv * (1.f / 192.f) + 1e-5f);
    const float* bp = base + (size_t)gw * CDIM;
    float* op = out + (size_t)gw * CDIM;
    op[lane]       = bp[lane]       + d0 * inv * g[lane]       + bt[lane];
    op[lane + 64]  = bp[lane + 64]  + d1 * inv * g[lane + 64]  + bt[lane + 64];
    op[lane + 128] = bp[lane + 128] + d2 * inv * g[lane + 128] + bt[lane + 128];
}

// ---------------- launch ----------------
extern "C" void kernel_launch(void* const* d_in, const int* in_sizes, int n_in,
                              void* d_out, int out_size, void* d_ws, size_t ws_size,
                              hipStream_t stream) {
    const float* x           = (const float*)d_in[0];
    const float* qkv_w       = (const float*)d_in[1];
    const float* q_bias      = (const float*)d_in[2];
    const float* v_bias      = (const float*)d_in[3];
    const float* logit_scale = (const float*)d_in[4];
    const float* cpb_w1      = (const float*)d_in[5];
    const float* cpb_b1      = (const float*)d_in[6];
    const float* cpb_w2      = (const float*)d_in[7];
    const float* proj_w      = (const float*)d_in[8];
    const float* proj_b      = (const float*)d_in[9];
    const float* norm1_g     = (const float*)d_in[10];
    const float* norm1_b     = (const float*)d_in[11];
    const float* fc1_w       = (const float*)d_in[12];
    const float* fc1_b       = (const float*)d_in[13];
    const float* fc2_w       = (const float*)d_in[14];
    const float* fc2_b       = (const float*)d_in[15];
    const float* norm2_g     = (const float*)d_in[16];
    const float* norm2_b     = (const float*)d_in[17];

    char* ws = (char*)d_ws;
    float* attnb = (float*)(ws + OFF_ATTN);
    float* qkv   = (float*)(ws + OFF_QKV);
    float* hbuf  = qkv;
    float* mbuf  = attnb;
    float* xa    = (float*)(ws + OFF_XA);
    float* x1    = (float*)(ws + OFF_X1);
    float* rpbT  = (float*)(ws + OFF_RPBT);
    float* hb    = (float*)(ws + OFF_HB);
    float* qkvb  = (float*)(ws + OFF_QKVB);
    int*   rmap  = (int*)(ws + OFF_RMAP);
    u16*   wsp   = (u16*)(ws + OFF_WSP);

    setup_misc<<<(MROW + 255) / 256, 256, 0, stream>>>(q_bias, v_bias, qkvb, rmap);
    split_w<<<(516096 + 255) / 256, 256, 0, stream>>>(qkv_w, proj_w, fc1_w, fc2_w, wsp);
    cpb_hidden<<<2197, 64, 0, stream>>>(cpb_w1, cpb_b1, cpb_w2, hb);
    cpb_rpb<<<484, 256, 0, stream>>>(hb, rpbT);

    gemm_mfma<false><<<dim3(5, 343), 256, 0, stream>>>(
        x, wsp + WQKV_HI, wsp + WQKV_LO, qkvb, qkv, 576, 192, rmap, nullptr);

    attn_mfma<<<NHEAD * 128, 512, 0, stream>>>(qkv, rpbT, logit_scale, attnb);

    gemm_mfma<false><<<dim3(2, 343), 256, 0, stream>>>(
        attnb, wsp + WPRJ_HI, wsp + WPRJ_LO, proj_b, xa, 192, 192, nullptr, rmap);

    ln_residual<<<MROW / 4, 256, 0, stream>>>(x, xa, norm1_g, norm1_b, x1);

    gemm_mfma<true><<<dim3(6, 343), 256, 0, stream>>>(
        x1, wsp + WFC1_HI, wsp + WFC1_LO, fc1_b, hbuf, 768, 192, nullptr, nullptr);

    gemm_mfma<false><<<dim3(2, 343), 256, 0, stream>>>(
        hbuf, wsp + WFC2_HI, wsp + WFC2_LO, fc2_b, mbuf, 192, 768, nullptr, nullptr);

    ln_residual<<<MROW / 4, 256, 0, stream>>>(x1, mbuf, norm2_g, norm2_b, (float*)d_out);
}